// Round 14
// baseline (269.047 us; speedup 1.0000x reference)
//
#include <hip/hip_runtime.h>
#include <math.h>

#define PI2f 6.28318530717958647692f

// B=16, Ci=Co=64, H=W=256, M1=M2=16. Modes j=0..31, freq f=(j<16)?j:j-32.
//
// ALL scratch lives inside d_out (67,108,864 floats = 1024 regions x 65536).
// Region-relative float offsets:
//   Ft slice bo : [0, 1024)      (mix2 -> inv_fused; 512 modes complex)
//   X  slice bi : [2048, 3072)   (fwd -> mix2; 512 modes complex)
//   Wm[m], m<512: [4096, 12288)  (prep2 -> mix2; Wm[m][i][o] complex, 8192 floats)
//   tw table    : region 0 [32768, 40960)  (prep2 -> fwd)
// inv_fused block bo stages its own Ft to LDS BEFORE overwriting its region.
//
// CORE RULE (rounds 5/11 post-mortems): every HBM cache line (128 B) must be
// produced/consumed in ONE visit. Split-line visits separated by compute get
// evicted from L2 (8 MB in-flight vs 4 MB/XCD) -> RMW fetch + write doubling.

static constexpr size_t REG = 65536;
static constexpr size_t TW_ABS = 32768;

// ---------------- prep2: W -> mode-major via LDS transpose + tw table ----------------
__global__ __launch_bounds__(256) void prep2(const float* __restrict__ w1,
                                             const float* __restrict__ w2,
                                             float* __restrict__ g) {
    const int b = blockIdx.x;
    const int t = threadIdx.x;
    if (b < 512) {
        __shared__ float ws[16 * 516];          // 33 KB
        const int wsel = b >> 8;                // 0: w1, 1: w2
        const int iob = b & 255;                // io-block (16 rows each)
        const float* src = (wsel ? w2 : w1) + (size_t)iob * 16 * 512;
#pragma unroll
        for (int q = 0; q < 8; q++) {
            int fid = q * 256 + t;              // float4 id 0..2047
            int row = fid >> 7, c = fid & 127;
            float4 v = *(const float4*)(src + (size_t)row * 512 + c * 4);
            *(float4*)(ws + row * 516 + c * 4) = v;
        }
        __syncthreads();
        const int m = t + (wsel << 8);
        float* dst = g + (size_t)m * REG + 4096 + (size_t)iob * 32;
#pragma unroll
        for (int rq = 0; rq < 8; rq++) {
            int r = rq * 2;
            float2 a  = *(const float2*)(ws + r * 516 + 2 * t);
            float2 bv = *(const float2*)(ws + (r + 1) * 516 + 2 * t);
            *(float4*)(dst + rq * 4) = make_float4(a.x, a.y, bv.x, bv.y);
        }
    } else {                                    // tw[w*16+k] = e^{-2pi i wk/256}
        int idx = (b - 512) * 256 + t;          // 0..4095
        int w = idx >> 4, k = idx & 15;
        int r = (w * k) & 255;                  // exact arg reduction
        float s, c;
        sincosf(PI2f * (float)r / 256.0f, &s, &c);
        g[TW_ABS + (size_t)idx * 2]     = c;
        g[TW_ABS + (size_t)idx * 2 + 1] = -s;
    }
}

// ---------------- forward: line-clean barrier-free W-DFT + H-DFT (round-12) ----------
// grid 1024: block = one (b,i) image, thread t owns row h=t entirely.
// Radix-2: A[k] = sum_{w<128} (x[w] + (-1)^k x[w+128]) e^{-2pi i k w/256}.
// 4 chunks x 32 pairs; per chunk burst-load BOTH full 128B lines so each line
// is fetched exactly once. s_load twiddles.
__global__ __launch_bounds__(256, 4) void fwd(const float* __restrict__ x,
                                              const float* __restrict__ twg,
                                              float* __restrict__ g) {
    __shared__ float As[16 * 516 + 4];          // [k][h] pad-2 complex, 33 KB
    const int t = threadIdx.x;
    const int bi = blockIdx.x;
    const float* xrow = x + (size_t)bi * 65536 + (size_t)t * 256;

    float ar[16], ai[16];
#pragma unroll
    for (int k = 0; k < 16; k++) { ar[k] = 0.f; ai[k] = 0.f; }

    for (int a = 0; a < 4; a++) {
        float4 lo[8], hi[8];                    // two full 128B lines of this row
#pragma unroll
        for (int q = 0; q < 8; q++) lo[q] = *(const float4*)(xrow + a * 32 + q * 4);
#pragma unroll
        for (int q = 0; q < 8; q++) hi[q] = *(const float4*)(xrow + a * 32 + 128 + q * 4);
#pragma unroll
        for (int q = 0; q < 8; q++) {
            float xe[4], xo[4];
            xe[0] = lo[q].x + hi[q].x; xo[0] = lo[q].x - hi[q].x;
            xe[1] = lo[q].y + hi[q].y; xo[1] = lo[q].y - hi[q].y;
            xe[2] = lo[q].z + hi[q].z; xo[2] = lo[q].z - hi[q].z;
            xe[3] = lo[q].w + hi[q].w; xo[3] = lo[q].w - hi[q].w;
#pragma unroll
            for (int e = 0; e < 4; e++) {
                const int w = a * 32 + q * 4 + e;           // pair index < 128
                const float* tp = twg + w * 32;             // uniform -> s_load
#pragma unroll
                for (int k = 0; k < 16; k++) {
                    float xv = (k & 1) ? xo[e] : xe[e];
                    ar[k] = fmaf(xv, tp[2 * k],     ar[k]);
                    ai[k] = fmaf(xv, tp[2 * k + 1], ai[k]);
                }
            }
        }
    }
    // transpose through LDS: As[k][h=t]
#pragma unroll
    for (int k = 0; k < 16; k++) {
        *(float2*)(As + k * 516 + t * 2) = make_float2(ar[k], ai[k]);
    }
    __syncthreads();

    // H-DFT: thread (jb = t>>4, k = t&15); h processed in pairs (b128 reads)
    const int k = t & 15, jb = t >> 4;
    const float* Ak = As + k * 516;
    float* Xp = g + (size_t)bi * REG + 2048;
    for (int half = 0; half < 2; half++) {
        int j = jb + half * 16;
        int f = (j < 16) ? j : j - 32;
        float s, c;
        sincosf(-PI2f * (float)f / 256.0f, &s, &c);
        float er = 1.f, ei = 0.f, accr = 0.f, acci = 0.f;
        for (int h = 0; h < 256; h += 2) {
            float4 a2 = *(const float4*)(Ak + 2 * h);
            accr = fmaf(a2.x, er, fmaf(-a2.y, ei, accr));
            acci = fmaf(a2.x, ei, fmaf( a2.y, er, acci));
            float nr = er * c - ei * s;
            ei = fmaf(er, s, ei * c);
            er = nr;
            accr = fmaf(a2.z, er, fmaf(-a2.w, ei, accr));
            acci = fmaf(a2.z, ei, fmaf( a2.w, er, acci));
            nr = er * c - ei * s;
            ei = fmaf(er, s, ei * c);
            er = nr;
        }
        *(float2*)(Xp + ((size_t)j * 16 + k) * 2) = make_float2(accr, acci);
    }
}

// ---------------- mix2: block per mode m; Ft[b][m][o] = sum_i X[b][i][m]*Wm[m][i][o] ----
__global__ __launch_bounds__(256, 4) void mix2(float* __restrict__ g) {
    __shared__ float Ws[8192];                  // Wm[m], 32 KB
    __shared__ float Xs[2048];                  // X[.][m] all (b,i), 8 KB
    const int m = blockIdx.x;                   // 0..511
    const int t = threadIdx.x;
    const float* Wp = g + (size_t)m * REG + 4096;
#pragma unroll
    for (int q = 0; q < 8; q++) {
        int fid = q * 256 + t;
        *(float4*)(Ws + fid * 4) = *(const float4*)(Wp + (size_t)fid * 4);
    }
#pragma unroll
    for (int q = 0; q < 4; q++) {
        int bi = q * 256 + t;
        float2 v = *(const float2*)(g + (size_t)bi * REG + 2048 + (size_t)m * 2);
        *(float2*)(Xs + bi * 2) = v;
    }
    __syncthreads();

    const int b = t >> 4, og = t & 15;          // o = og*4 + 0..3
    float acr[4] = {0.f, 0.f, 0.f, 0.f}, aci[4] = {0.f, 0.f, 0.f, 0.f};
    const float* Wb = Ws + og * 8;              // + i*128
    const float* Xb = Xs + b * 128;             // + i*2
    for (int i = 0; i < 64; i++) {
        float2 xv = *(const float2*)(Xb + 2 * i);
        float4 w0 = *(const float4*)(Wb + i * 128);
        float4 w1v = *(const float4*)(Wb + i * 128 + 4);
        acr[0] = fmaf(xv.x, w0.x, fmaf(-xv.y, w0.y, acr[0]));
        aci[0] = fmaf(xv.x, w0.y, fmaf( xv.y, w0.x, aci[0]));
        acr[1] = fmaf(xv.x, w0.z, fmaf(-xv.y, w0.w, acr[1]));
        aci[1] = fmaf(xv.x, w0.w, fmaf( xv.y, w0.z, aci[1]));
        acr[2] = fmaf(xv.x, w1v.x, fmaf(-xv.y, w1v.y, acr[2]));
        aci[2] = fmaf(xv.x, w1v.y, fmaf( xv.y, w1v.x, aci[2]));
        acr[3] = fmaf(xv.x, w1v.z, fmaf(-xv.y, w1v.w, acr[3]));
        aci[3] = fmaf(xv.x, w1v.w, fmaf( xv.y, w1v.z, aci[3]));
    }
#pragma unroll
    for (int oo = 0; oo < 4; oo++) {
        int o = og * 4 + oo;
        *(float2*)(g + (size_t)(b * 64 + o) * REG + (size_t)m * 2) = make_float2(acr[oo], aci[oo]);
    }
}

// ---------------- inverse: H-iDFT + irfft-W, shared-pq mirror lines ----------
// block = one bo region; thread t owns output row h=t.
// Phase 2: 4 rounds; round a computes pq ONCE for m = 32a..32a+32 (33 calls)
// and emits TWO full 128B lines: lo cols [32a,32a+32) = P-Q at m=col, and
// hi cols [224-32a, 256-32a) = P+Q at m=256-col (m=32a+1..32a+32, 31 shared).
// Cols 0 and 128 automatic (sin=0 -> Q=0). 132 pq calls vs 256 (round 12).
__global__ __launch_bounds__(256, 4) void inv_fused(float* __restrict__ g) {
    __shared__ float Fs[1024];                  // Ft slice, 4 KB
    __shared__ float phS[512];                  // cos/sin(2pi m/256), 2 KB
    __shared__ float T[256 * 32];               // swizzled transpose tile, 32 KB
    const int t = threadIdx.x;
    const int bo = blockIdx.x;
    float* regn = g + (size_t)bo * REG;

    // stage own Ft slice BEFORE any output write
    *(float4*)(Fs + t * 4) = *(const float4*)(regn + (size_t)t * 4);
    float rs, rc;
    sincosf(PI2f * (float)t / 256.0f, &rs, &rc);
    phS[t * 2] = rc; phS[t * 2 + 1] = rs;
    __syncthreads();

    // phase 1: Y[h=t][k] = sum_f Ft[j(f)][k] e^{+2pi i f t/256}; k in pairs (b128)
    float Yr[16], Yi[16];
#pragma unroll
    for (int k = 0; k < 16; k++) { Yr[k] = 0.f; Yi[k] = 0.f; }
    float es, ec;
    sincosf(-PI2f * (float)(t & 15) / 16.0f, &es, &ec);
    float er = ec, ei = es;
    for (int sdx = 0; sdx < 32; sdx++) {                // f = sdx-16
        int j = (sdx < 16) ? sdx + 16 : sdx - 16;
        const float* fj = Fs + j * 32;
#pragma unroll
        for (int kq = 0; kq < 8; kq++) {
            float4 fv = *(const float4*)(fj + 4 * kq);  // broadcast
            Yr[2 * kq]     = fmaf(fv.x, er, fmaf(-fv.y, ei, Yr[2 * kq]));
            Yi[2 * kq]     = fmaf(fv.x, ei, fmaf( fv.y, er, Yi[2 * kq]));
            Yr[2 * kq + 1] = fmaf(fv.z, er, fmaf(-fv.w, ei, Yr[2 * kq + 1]));
            Yi[2 * kq + 1] = fmaf(fv.z, ei, fmaf( fv.w, er, Yi[2 * kq + 1]));
        }
        float nr = er * rc - ei * rs;
        ei = fmaf(er, rs, ei * rc);
        er = nr;
    }

    const float INV = 1.0f / 65536.0f;
    Yr[0] *= INV;
#pragma unroll
    for (int k = 1; k < 16; k++) { Yr[k] *= 2.0f * INV; Yi[k] *= 2.0f * INV; }

    auto pq = [&](float c, float s, float& P, float& Q) {
        float c2 = c + c;
        float Cp = c, Cpp = 1.f, Sp = s, Spp = 0.f;
        P = fmaf(Yr[1], c, Yr[0]);
        Q = Yi[1] * s;
#pragma unroll
        for (int k = 2; k < 16; k++) {          // Chebyshev 3-term
            float Cn = fmaf(c2, Cp, -Cpp);
            float Sn = fmaf(c2, Sp, -Spp);
            P = fmaf(Yr[k], Cn, P);
            Q = fmaf(Yi[k], Sn, Q);
            Cpp = Cp; Cp = Cn; Spp = Sp; Sp = Sn;
        }
    };

    const int sw = t & 7;                       // swizzle key for own row
    const int rsub = t >> 3, f4 = t & 7;        // store lane roles
    for (int a = 0; a < 4; a++) {
        float lov[32], hiv[32];
#pragma unroll
        for (int mm = 0; mm <= 32; mm++) {
            int m = 32 * a + mm;
            float P, Q;
            pq(phS[2 * m], phS[2 * m + 1], P, Q);
            if (mm < 32) lov[mm] = P - Q;       // lo col 32a+mm
            if (mm >= 1) hiv[32 - mm] = P + Q;  // hi col (224-32a)+(32-mm)
        }
        // ---- lo line: cols [32a, 32a+32) ----
        __syncthreads();                        // prev visit's T reads done
        float* Tr = T + t * 32;
#pragma unroll
        for (int q4 = 0; q4 < 8; q4++) {
            *(float4*)(Tr + ((q4 ^ sw) * 4)) =
                make_float4(lov[q4 * 4], lov[q4 * 4 + 1], lov[q4 * 4 + 2], lov[q4 * 4 + 3]);
        }
        __syncthreads();
#pragma unroll
        for (int it = 0; it < 8; it++) {
            int row = it * 32 + rsub;
            float4 v = *(const float4*)(T + row * 32 + ((f4 ^ (row & 7)) * 4));
            *(float4*)(regn + (size_t)row * 256 + a * 32 + f4 * 4) = v;
        }
        // ---- hi line: cols [224-32a, 256-32a) ----
        __syncthreads();
#pragma unroll
        for (int q4 = 0; q4 < 8; q4++) {
            *(float4*)(Tr + ((q4 ^ sw) * 4)) =
                make_float4(hiv[q4 * 4], hiv[q4 * 4 + 1], hiv[q4 * 4 + 2], hiv[q4 * 4 + 3]);
        }
        __syncthreads();
        const int cb2 = 224 - a * 32;
#pragma unroll
        for (int it = 0; it < 8; it++) {
            int row = it * 32 + rsub;
            float4 v = *(const float4*)(T + row * 32 + ((f4 ^ (row & 7)) * 4));
            *(float4*)(regn + (size_t)row * 256 + cb2 + f4 * 4) = v;
        }
    }
}

extern "C" void kernel_launch(void* const* d_in, const int* in_sizes, int n_in,
                              void* d_out, int out_size, void* d_ws, size_t ws_size,
                              hipStream_t stream) {
    const float* x  = (const float*)d_in[0];
    const float* w1 = (const float*)d_in[1];
    const float* w2 = (const float*)d_in[2];
    float* g = (float*)d_out;
    (void)d_ws; (void)ws_size;

    prep2    <<<528,  256, 0, stream>>>(w1, w2, g);
    fwd      <<<1024, 256, 0, stream>>>(x, g + TW_ABS, g);
    mix2     <<<512,  256, 0, stream>>>(g);
    inv_fused<<<1024, 256, 0, stream>>>(g);
}

// Round 16
// 205.517 us; speedup vs baseline: 1.3091x; 1.3091x over previous
//
#include <hip/hip_runtime.h>
#include <math.h>

#define PI2f 6.28318530717958647692f

// B=16, Ci=Co=64, H=W=256, M1=M2=16. Modes j=0..31, freq f=(j<16)?j:j-32.
//
// ALL scratch lives inside d_out (67,108,864 floats = 1024 regions x 65536).
// Region-relative float offsets:
//   Ft slice bo : [0, 1024)      (mix2 -> inv_fused; 512 modes complex)
//   X  slice bi : [2048, 3072)   (fwd -> mix2; 512 modes complex)
//   Wm[m], m<512: [4096, 12288)  (prep2 -> mix2; Wm[m][i][o] complex, 8192 floats)
//   tw table    : region 0 [32768, 40960)  (prep2 -> fwd)
// inv_fused block bo stages its own Ft to LDS BEFORE overwriting its region.
//
// CORE RULES (post-mortems r5/r7/r11/r13/r14):
//  1. Every HBM cache line (128 B) produced/consumed in ONE temporally-tight
//     visit (split visits -> L2 eviction -> RMW fetch + write doubling).
//  2. VGPR budget at (256,4) is ~110 live floats; FLOP savings that add more
//     registers than that SPILL and lose (r7: 440us, r13: +10, r14: +30).

static constexpr size_t REG = 65536;
static constexpr size_t TW_ABS = 32768;

typedef float fx4 __attribute__((ext_vector_type(4)));  // native vec for NT stores

// ---------------- prep2: W -> mode-major via LDS transpose + tw table ----------------
__global__ __launch_bounds__(256) void prep2(const float* __restrict__ w1,
                                             const float* __restrict__ w2,
                                             float* __restrict__ g) {
    const int b = blockIdx.x;
    const int t = threadIdx.x;
    if (b < 512) {
        __shared__ float ws[16 * 516];          // 33 KB
        const int wsel = b >> 8;                // 0: w1, 1: w2
        const int iob = b & 255;                // io-block (16 rows each)
        const float* src = (wsel ? w2 : w1) + (size_t)iob * 16 * 512;
#pragma unroll
        for (int q = 0; q < 8; q++) {
            int fid = q * 256 + t;              // float4 id 0..2047
            int row = fid >> 7, c = fid & 127;
            float4 v = *(const float4*)(src + (size_t)row * 512 + c * 4);
            *(float4*)(ws + row * 516 + c * 4) = v;
        }
        __syncthreads();
        const int m = t + (wsel << 8);
        float* dst = g + (size_t)m * REG + 4096 + (size_t)iob * 32;
#pragma unroll
        for (int rq = 0; rq < 8; rq++) {
            int r = rq * 2;
            float2 a  = *(const float2*)(ws + r * 516 + 2 * t);
            float2 bv = *(const float2*)(ws + (r + 1) * 516 + 2 * t);
            *(float4*)(dst + rq * 4) = make_float4(a.x, a.y, bv.x, bv.y);
        }
    } else {                                    // tw[w*16+k] = e^{-2pi i wk/256}
        int idx = (b - 512) * 256 + t;          // 0..4095
        int w = idx >> 4, k = idx & 15;
        int r = (w * k) & 255;                  // exact arg reduction
        float s, c;
        sincosf(PI2f * (float)r / 256.0f, &s, &c);
        g[TW_ABS + (size_t)idx * 2]     = c;
        g[TW_ABS + (size_t)idx * 2 + 1] = -s;
    }
}

// ---------------- forward: line-clean W-DFT (round-12) + parity-split H-DFT ----------
// grid 1024: block = one (b,i) image, thread t owns row h=t entirely.
// W: radix-2 pairs, 4 chunks x 32 pairs, burst-load both full 128B lines.
// H: parity split, X[j] = sum_{h'<128} (A[h'] + (-1)^f A[h'+128]) e^{-2pi i f h'/256};
//    thread's two modes (f=jb, f=jb-16) share parity -> one combo, two rotators.
__global__ __launch_bounds__(256, 4) void fwd(const float* __restrict__ x,
                                              const float* __restrict__ twg,
                                              float* __restrict__ g) {
    __shared__ float As[16 * 516 + 4];          // [k][h] pad-2 complex, 33 KB
    const int t = threadIdx.x;
    const int bi = blockIdx.x;
    const float* xrow = x + (size_t)bi * 65536 + (size_t)t * 256;

    float ar[16], ai[16];
#pragma unroll
    for (int k = 0; k < 16; k++) { ar[k] = 0.f; ai[k] = 0.f; }

    for (int a = 0; a < 4; a++) {
        float4 lo[8], hi[8];                    // two full 128B lines of this row
#pragma unroll
        for (int q = 0; q < 8; q++) lo[q] = *(const float4*)(xrow + a * 32 + q * 4);
#pragma unroll
        for (int q = 0; q < 8; q++) hi[q] = *(const float4*)(xrow + a * 32 + 128 + q * 4);
#pragma unroll
        for (int q = 0; q < 8; q++) {
            float xe[4], xo[4];
            xe[0] = lo[q].x + hi[q].x; xo[0] = lo[q].x - hi[q].x;
            xe[1] = lo[q].y + hi[q].y; xo[1] = lo[q].y - hi[q].y;
            xe[2] = lo[q].z + hi[q].z; xo[2] = lo[q].z - hi[q].z;
            xe[3] = lo[q].w + hi[q].w; xo[3] = lo[q].w - hi[q].w;
#pragma unroll
            for (int e = 0; e < 4; e++) {
                const int w = a * 32 + q * 4 + e;           // pair index < 128
                const float* tp = twg + w * 32;             // uniform -> s_load
#pragma unroll
                for (int k = 0; k < 16; k++) {
                    float xv = (k & 1) ? xo[e] : xe[e];
                    ar[k] = fmaf(xv, tp[2 * k],     ar[k]);
                    ai[k] = fmaf(xv, tp[2 * k + 1], ai[k]);
                }
            }
        }
    }
    // transpose through LDS: As[k][h=t]
#pragma unroll
    for (int k = 0; k < 16; k++) {
        *(float2*)(As + k * 516 + t * 2) = make_float2(ar[k], ai[k]);
    }
    __syncthreads();

    // H-DFT, parity split. Thread (jb = t>>4, k = t&15): modes j=jb (f=jb) and
    // j=jb+16 (f=jb-16); (-1)^f identical for both.
    const int k = t & 15, jb = t >> 4;
    const float* Ak = As + k * 516;
    float* Xp = g + (size_t)bi * REG + 2048;
    const float sgn = (jb & 1) ? -1.0f : 1.0f;  // (-1)^f
    float s1, c1, s2, c2;
    sincosf(-PI2f * (float)jb / 256.0f, &s1, &c1);
    sincosf(-PI2f * (float)(jb - 16) / 256.0f, &s2, &c2);
    float e1r = 1.f, e1i = 0.f, a1r = 0.f, a1i = 0.f;
    float e2r = 1.f, e2i = 0.f, a2r = 0.f, a2i = 0.f;
    for (int hp = 0; hp < 128; hp += 2) {
        float4 lo4 = *(const float4*)(Ak + 2 * hp);          // h', h'+1
        float4 hi4 = *(const float4*)(Ak + 2 * (hp + 128));  // h'+128, h'+129
#pragma unroll
        for (int e = 0; e < 2; e++) {
            float cr = fmaf(sgn, e ? hi4.z : hi4.x, e ? lo4.z : lo4.x);
            float ci = fmaf(sgn, e ? hi4.w : hi4.y, e ? lo4.w : lo4.y);
            a1r = fmaf(cr, e1r, fmaf(-ci, e1i, a1r));
            a1i = fmaf(cr, e1i, fmaf( ci, e1r, a1i));
            float n1 = e1r * c1 - e1i * s1;
            e1i = fmaf(e1r, s1, e1i * c1);
            e1r = n1;
            a2r = fmaf(cr, e2r, fmaf(-ci, e2i, a2r));
            a2i = fmaf(cr, e2i, fmaf( ci, e2r, a2i));
            float n2 = e2r * c2 - e2i * s2;
            e2i = fmaf(e2r, s2, e2i * c2);
            e2r = n2;
        }
    }
    *(float2*)(Xp + ((size_t)jb * 16 + k) * 2)        = make_float2(a1r, a1i);
    *(float2*)(Xp + ((size_t)(jb + 16) * 16 + k) * 2) = make_float2(a2r, a2i);
}

// ---------------- mix2: block per mode m; Ft[b][m][o] = sum_i X[b][i][m]*Wm[m][i][o] ----
__global__ __launch_bounds__(256, 4) void mix2(float* __restrict__ g) {
    __shared__ float Ws[8192];                  // Wm[m], 32 KB
    __shared__ float Xs[2048];                  // X[.][m] all (b,i), 8 KB
    const int m = blockIdx.x;                   // 0..511
    const int t = threadIdx.x;
    const float* Wp = g + (size_t)m * REG + 4096;
#pragma unroll
    for (int q = 0; q < 8; q++) {
        int fid = q * 256 + t;
        *(float4*)(Ws + fid * 4) = *(const float4*)(Wp + (size_t)fid * 4);
    }
#pragma unroll
    for (int q = 0; q < 4; q++) {
        int bi = q * 256 + t;
        float2 v = *(const float2*)(g + (size_t)bi * REG + 2048 + (size_t)m * 2);
        *(float2*)(Xs + bi * 2) = v;
    }
    __syncthreads();

    const int b = t >> 4, og = t & 15;          // o = og*4 + 0..3
    float acr[4] = {0.f, 0.f, 0.f, 0.f}, aci[4] = {0.f, 0.f, 0.f, 0.f};
    const float* Wb = Ws + og * 8;              // + i*128
    const float* Xb = Xs + b * 128;             // + i*2
    for (int i = 0; i < 64; i++) {
        float2 xv = *(const float2*)(Xb + 2 * i);
        float4 w0 = *(const float4*)(Wb + i * 128);
        float4 w1v = *(const float4*)(Wb + i * 128 + 4);
        acr[0] = fmaf(xv.x, w0.x, fmaf(-xv.y, w0.y, acr[0]));
        aci[0] = fmaf(xv.x, w0.y, fmaf( xv.y, w0.x, aci[0]));
        acr[1] = fmaf(xv.x, w0.z, fmaf(-xv.y, w0.w, acr[1]));
        aci[1] = fmaf(xv.x, w0.w, fmaf( xv.y, w0.z, aci[1]));
        acr[2] = fmaf(xv.x, w1v.x, fmaf(-xv.y, w1v.y, acr[2]));
        aci[2] = fmaf(xv.x, w1v.y, fmaf( xv.y, w1v.x, aci[2]));
        acr[3] = fmaf(xv.x, w1v.z, fmaf(-xv.y, w1v.w, acr[3]));
        aci[3] = fmaf(xv.x, w1v.w, fmaf( xv.y, w1v.z, aci[3]));
    }
#pragma unroll
    for (int oo = 0; oo < 4; oo++) {
        int o = og * 4 + oo;
        *(float2*)(g + (size_t)(b * 64 + o) * REG + (size_t)m * 2) = make_float2(acr[oo], aci[oo]);
    }
}

// ---------------- inverse: H-iDFT + irfft-W, single-visit full-line NT stores --------
// block = one bo region; thread t owns output row h=t.
// Phase 2 (round-12): 8 visits, visit a covers cols [32a, 32a+32) = one 128B
// line/row. a<4: P-Q at m=col; a>=4: P+Q at m=256-col. Output stores are
// nontemporal (native ext_vector type): 268MB streamed once, never re-read.
__global__ __launch_bounds__(256, 4) void inv_fused(float* __restrict__ g) {
    __shared__ float Fs[1024];                  // Ft slice, 4 KB
    __shared__ float phS[512];                  // cos/sin(2pi m/256), 2 KB
    __shared__ float T[256 * 32];               // swizzled transpose tile, 32 KB
    const int t = threadIdx.x;
    const int bo = blockIdx.x;
    float* regn = g + (size_t)bo * REG;

    // stage own Ft slice BEFORE any output write
    *(float4*)(Fs + t * 4) = *(const float4*)(regn + (size_t)t * 4);
    float rs, rc;
    sincosf(PI2f * (float)t / 256.0f, &rs, &rc);
    phS[t * 2] = rc; phS[t * 2 + 1] = rs;
    __syncthreads();

    // phase 1: Y[h=t][k] = sum_f Ft[j(f)][k] e^{+2pi i f t/256}; k in pairs (b128)
    float Yr[16], Yi[16];
#pragma unroll
    for (int k = 0; k < 16; k++) { Yr[k] = 0.f; Yi[k] = 0.f; }
    float es, ec;
    sincosf(-PI2f * (float)(t & 15) / 16.0f, &es, &ec);
    float er = ec, ei = es;
    for (int sdx = 0; sdx < 32; sdx++) {                // f = sdx-16
        int j = (sdx < 16) ? sdx + 16 : sdx - 16;
        const float* fj = Fs + j * 32;
#pragma unroll
        for (int kq = 0; kq < 8; kq++) {
            float4 fv = *(const float4*)(fj + 4 * kq);  // broadcast
            Yr[2 * kq]     = fmaf(fv.x, er, fmaf(-fv.y, ei, Yr[2 * kq]));
            Yi[2 * kq]     = fmaf(fv.x, ei, fmaf( fv.y, er, Yi[2 * kq]));
            Yr[2 * kq + 1] = fmaf(fv.z, er, fmaf(-fv.w, ei, Yr[2 * kq + 1]));
            Yi[2 * kq + 1] = fmaf(fv.z, ei, fmaf( fv.w, er, Yi[2 * kq + 1]));
        }
        float nr = er * rc - ei * rs;
        ei = fmaf(er, rs, ei * rc);
        er = nr;
    }

    const float INV = 1.0f / 65536.0f;
    Yr[0] *= INV;
#pragma unroll
    for (int k = 1; k < 16; k++) { Yr[k] *= 2.0f * INV; Yi[k] *= 2.0f * INV; }

    auto pq = [&](float c, float s, float& P, float& Q) {
        float c2 = c + c;
        float Cp = c, Cpp = 1.f, Sp = s, Spp = 0.f;
        P = fmaf(Yr[1], c, Yr[0]);
        Q = Yi[1] * s;
#pragma unroll
        for (int k = 2; k < 16; k++) {          // Chebyshev 3-term
            float Cn = fmaf(c2, Cp, -Cpp);
            float Sn = fmaf(c2, Sp, -Spp);
            P = fmaf(Yr[k], Cn, P);
            Q = fmaf(Yi[k], Sn, Q);
            Cpp = Cp; Cp = Cn; Spp = Sp; Sp = Sn;
        }
    };

    const int sw = t & 7;                       // swizzle key for own row
    const int rsub = t >> 3, f4 = t & 7;        // store lane roles
    for (int a = 0; a < 8; a++) {
        float val[32];
#pragma unroll
        for (int q = 0; q < 32; q++) {
            int col = a * 32 + q;
            int m = (a < 4) ? col : 256 - col;
            float P, Q;
            pq(phS[2 * m], phS[2 * m + 1], P, Q);
            val[q] = (a < 4) ? (P - Q) : (P + Q);
        }
        __syncthreads();                        // prev visit's T reads done
        float* Tr = T + t * 32;
#pragma unroll
        for (int q4 = 0; q4 < 8; q4++) {
            *(float4*)(Tr + ((q4 ^ sw) * 4)) =
                make_float4(val[q4 * 4], val[q4 * 4 + 1], val[q4 * 4 + 2], val[q4 * 4 + 3]);
        }
        __syncthreads();
        // store: 8 lanes x float4 = one full 128B line per row, single visit, NT
#pragma unroll
        for (int it = 0; it < 8; it++) {
            int row = it * 32 + rsub;
            fx4 v = *(const fx4*)(T + row * 32 + ((f4 ^ (row & 7)) * 4));
            __builtin_nontemporal_store(v, (fx4*)(regn + (size_t)row * 256 + a * 32 + f4 * 4));
        }
    }
}

extern "C" void kernel_launch(void* const* d_in, const int* in_sizes, int n_in,
                              void* d_out, int out_size, void* d_ws, size_t ws_size,
                              hipStream_t stream) {
    const float* x  = (const float*)d_in[0];
    const float* w1 = (const float*)d_in[1];
    const float* w2 = (const float*)d_in[2];
    float* g = (float*)d_out;
    (void)d_ws; (void)ws_size;

    prep2    <<<528,  256, 0, stream>>>(w1, w2, g);
    fwd      <<<1024, 256, 0, stream>>>(x, g + TW_ABS, g);
    mix2     <<<512,  256, 0, stream>>>(g);
    inv_fused<<<1024, 256, 0, stream>>>(g);
}